// Round 13
// baseline (1715.587 us; speedup 1.0000x reference)
//
#include <hip/hip_runtime.h>
#include <hip/hip_bf16.h>
#include <math.h>

#define BATCH 4
#define SEQ 2048
#define DMODEL 768
#define NLAYER 8
#define DINNER 1536
#define HEADDIM 64
#define NHEADS 24
#define DSTATE 128
#define CONVDIM 1792
#define DINPROJ 3352
#define NPAD 3456
#define NPADW 3584
#define ROWS (BATCH*SEQ)
#define EPS 1e-5f
#define QCH 128
#define NCH (SEQ/QCH)

typedef __bf16 bf16;
typedef bf16 bf16x8 __attribute__((ext_vector_type(8)));
typedef bf16 bf16x4 __attribute__((ext_vector_type(4)));
typedef float f32x4 __attribute__((ext_vector_type(4)));

#define GLD(src, dst) __builtin_amdgcn_global_load_lds( \
    (const __attribute__((address_space(1))) void*)(src), \
    (__attribute__((address_space(3))) void*)(dst), 16, 0, 0)

__device__ __forceinline__ void bar_sync() {
    asm volatile("" ::: "memory");
    __builtin_amdgcn_s_barrier();
    asm volatile("" ::: "memory");
}

__device__ __forceinline__ float fsilu(float x) { return x / (1.f + __expf(-x)); }

// ---------------- embed: res = x @ W_emb^T + b_emb (4 outputs/thread) ----------------
__global__ void k_embed(const float* __restrict__ x, const float* __restrict__ We,
                        const float* __restrict__ be, float* __restrict__ res) {
    int idx = blockIdx.x * 256 + threadIdx.x;          // ROWS * DMODEL/4
    int d0 = (idx % (DMODEL / 4)) * 4;
    int bl = idx / (DMODEL / 4);
    float xv[6];
#pragma unroll
    for (int i = 0; i < 6; ++i) xv[i] = x[bl * 6 + i];
    float4 o;
    float* op = &o.x;
#pragma unroll
    for (int j = 0; j < 4; ++j) {
        float acc = be[d0 + j];
#pragma unroll
        for (int i = 0; i < 6; ++i) acc += xv[i] * We[(d0 + j) * 6 + i];
        op[j] = acc;
    }
    *(float4*)(res + (long)bl * DMODEL + d0) = o;
}

// ---------------- read-only rmsnorm (vectorized, 192 thr x float4) ----------------
__global__ __launch_bounds__(192) void k_rmsnorm(const float* __restrict__ res,
                                                 const float* __restrict__ w,
                                                 bf16* __restrict__ out) {
    __shared__ float sm[3];
    int r = blockIdx.x, tid = threadIdx.x;
    int d0 = tid * 4;
    float4 v = *(const float4*)(res + (long)r * DMODEL + d0);
    float ss = v.x * v.x + v.y * v.y + v.z * v.z + v.w * v.w;
#pragma unroll
    for (int off = 32; off; off >>= 1) ss += __shfl_down(ss, off, 64);
    if ((tid & 63) == 0) sm[tid >> 6] = ss;
    __syncthreads();
    float sc = rsqrtf((sm[0] + sm[1] + sm[2]) / (float)DMODEL + EPS);
    float4 wv = *(const float4*)(w + d0);
    bf16x4 o;
    o[0] = (bf16)(v.x * sc * wv.x);
    o[1] = (bf16)(v.y * sc * wv.y);
    o[2] = (bf16)(v.z * sc * wv.z);
    o[3] = (bf16)(v.w * sc * wv.w);
    *(bf16x4*)(out + (long)r * DMODEL + d0) = o;
}

// ---------------- batched weight conversions (vectorized x4) ----------------
__global__ void k_cvt_in(const float* __restrict__ src, bf16* __restrict__ dst) {
    long e = ((long)blockIdx.x * 256 + threadIdx.x) * 4;   // NLAYER*NPADW*DMODEL elems
    int l = (int)(e / (NPADW * DMODEL));
    long rem = e % (NPADW * DMODEL);
    int n = (int)(rem / DMODEL);
    int d = (int)(rem % DMODEL);
    bf16x4 o;
    if (n < DINPROJ) {
        float4 v = *(const float4*)(src + ((long)l * DINPROJ + n) * DMODEL + d);
        o[0] = (bf16)v.x; o[1] = (bf16)v.y; o[2] = (bf16)v.z; o[3] = (bf16)v.w;
    } else {
        o[0] = (bf16)0.f; o[1] = (bf16)0.f; o[2] = (bf16)0.f; o[3] = (bf16)0.f;
    }
    *(bf16x4*)(dst + e) = o;
}
__global__ void k_cvt_out(const float* __restrict__ src, bf16* __restrict__ dst) {
    long e = ((long)blockIdx.x * 256 + threadIdx.x) * 4;
    float4 v = *(const float4*)(src + e);
    bf16x4 o;
    o[0] = (bf16)v.x; o[1] = (bf16)v.y; o[2] = (bf16)v.z; o[3] = (bf16)v.w;
    *(bf16x4*)(dst + e) = o;
}

// ---------------- bf16 MFMA GEMM: C[M,N] (=|+=) A[M,K] @ B[N,K]^T ----------------
// BMxBN tile, template BK, counted-vmcnt depth-2 pipeline, XOR-swizzled LDS.
template <typename OT, int BM, int BN, int BK, int TH, bool ACC>
__global__ __launch_bounds__(TH) void k_gemm(const bf16* __restrict__ A, const bf16* __restrict__ B,
                                             OT* __restrict__ C, int K, int ldc, int Nact) {
    constexpr int NW  = TH / 64;
    constexpr int nWn = (BN / 64 < 4) ? BN / 64 : 4;
    constexpr int nWm = NW / nWn;
    constexpr int WMR = BM / nWm;
    constexpr int MI  = WMR / 16;
    constexpr int MH  = MI / 2;
    constexpr int NI  = 4;
    constexpr int CPR = BK / 8;          // 16B chunks per LDS row
    constexpr int RG  = TH / CPR;        // rows per GLD group
    constexpr int AG  = BM / RG;
    constexpr int BG  = BN / RG;
    constexpr int KS  = BK / 32;         // k-slices per tile
    constexpr int RSB = BK * 2;          // LDS row stride bytes
    __shared__ bf16 As[2][BM * BK];
    __shared__ bf16 Bs[2][BN * BK];
    const int tid = threadIdx.x;
    const int lane = tid & 63;
    const int w = tid >> 6;
    const int wm = w / nWn, wn = w % nWn;
    const long rowA0 = (long)blockIdx.x * BM;
    const long rowB0 = (long)blockIdx.y * BN;
    const int srow = tid / CPR;
    const int scol = ((tid & (CPR - 1)) ^ (srow & (CPR - 1))) * 8;
    const bf16* Ab = A + rowA0 * K + scol;
    const bf16* Bb = B + rowB0 * K + scol;

    f32x4 acc[MI][NI];
    const f32x4 vz = {0.f, 0.f, 0.f, 0.f};
#pragma unroll
    for (int mi = 0; mi < MI; ++mi)
#pragma unroll
        for (int ni = 0; ni < NI; ++ni) acc[mi][ni] = vz;

    auto stage = [&](int buf, int kt) {
#pragma unroll
        for (int j = 0; j < AG; ++j)
            GLD(Ab + (long)(j * RG + srow) * K + kt, &As[buf][(j * TH + w * 64) * 8]);
#pragma unroll
        for (int j = 0; j < BG; ++j)
            GLD(Bb + (long)(j * RG + srow) * K + kt, &Bs[buf][(j * TH + w * 64) * 8]);
    };
    auto waitv = [&]() {   // allow the newest stage's loads to stay outstanding
        if constexpr (AG + BG == 4)      asm volatile("s_waitcnt vmcnt(4)" ::: "memory");
        else if constexpr (AG + BG == 6) asm volatile("s_waitcnt vmcnt(6)" ::: "memory");
        else                             asm volatile("s_waitcnt vmcnt(8)" ::: "memory");
    };

    bf16x8 bfr[NI][KS];
    bf16x8 af[MH][KS];
    auto rd_bfr = [&](int buf) {
        const char* BsB = (const char*)Bs[buf];
#pragma unroll
        for (int ni = 0; ni < NI; ++ni)
#pragma unroll
            for (int ks = 0; ks < KS; ++ks) {
                int r = wn * 64 + ni * 16 + (lane & 15);
                bfr[ni][ks] = *(const bf16x8*)(BsB + r * RSB + ((ks * 64 + (lane >> 4) * 16) ^ ((r & (CPR - 1)) << 4)));
            }
    };
    auto rd_af = [&](int buf, int m0) {
        const char* AsB = (const char*)As[buf];
#pragma unroll
        for (int mi = 0; mi < MH; ++mi)
#pragma unroll
            for (int ks = 0; ks < KS; ++ks) {
                int r = wm * WMR + (m0 + mi) * 16 + (lane & 15);
                af[mi][ks] = *(const bf16x8*)(AsB + r * RSB + ((ks * 64 + (lane >> 4) * 16) ^ ((r & (CPR - 1)) << 4)));
            }
    };
    auto do_half = [&](int m0) {
#pragma unroll
        for (int mi = 0; mi < MH; ++mi)
#pragma unroll
            for (int ni = 0; ni < NI; ++ni)
#pragma unroll
                for (int ks = 0; ks < KS; ++ks)
                    acc[m0 + mi][ni] = __builtin_amdgcn_mfma_f32_16x16x32_bf16(af[mi][ks], bfr[ni][ks], acc[m0 + mi][ni], 0, 0, 0);
    };

    const int NT = K / BK;
    stage(0, 0);
    stage(1, BK);
    for (int t = 0; t < NT - 2; ++t) {
        waitv();
        bar_sync();
        rd_bfr(t & 1);
        rd_af(t & 1, 0);
        do_half(0);
        rd_af(t & 1, MH);
        asm volatile("s_waitcnt lgkmcnt(0)" ::: "memory");
        bar_sync();
        stage(t & 1, (t + 2) * BK);
        __builtin_amdgcn_sched_barrier(0);
        do_half(MH);
    }
    {
        waitv();
        bar_sync();
        rd_bfr((NT - 2) & 1);
        rd_af((NT - 2) & 1, 0);
        do_half(0);
        rd_af((NT - 2) & 1, MH);
        do_half(MH);
    }
    {
        asm volatile("s_waitcnt vmcnt(0)" ::: "memory");
        bar_sync();
        rd_bfr((NT - 1) & 1);
        rd_af((NT - 1) & 1, 0);
        do_half(0);
        rd_af((NT - 1) & 1, MH);
        do_half(MH);
    }

    const int crow = (lane >> 4) * 4;
    const int ccol = lane & 15;
#pragma unroll
    for (int mi = 0; mi < MI; ++mi)
#pragma unroll
        for (int ni = 0; ni < NI; ++ni) {
            long r0 = rowA0 + wm * WMR + mi * 16 + crow;
            long c0 = rowB0 + wn * 64 + ni * 16 + ccol;
            if ((int)c0 < Nact) {
#pragma unroll
                for (int j = 0; j < 4; ++j) {
                    if constexpr (ACC) C[(r0 + j) * ldc + c0] += (OT)acc[mi][ni][j];
                    else               C[(r0 + j) * ldc + c0]  = (OT)acc[mi][ni][j];
                }
            }
        }
}

// ---------------- slim conv for B/C channels only -> bc[ROWS][256] ----------------
__global__ void k_convBC(const bf16* __restrict__ zx, const float* __restrict__ cw,
                         const float* __restrict__ cb, bf16* __restrict__ bc) {
    int idx = blockIdx.x * 256 + threadIdx.x;   // ROWS * 32
    int c8 = idx & 31; int blt = idx >> 5;
    int t = blt % SEQ;
    int ch = DINNER + c8 * 8;
    long bbase = (long)(blt - t) * NPAD;
    float cwa[8][4];
#pragma unroll
    for (int j = 0; j < 8; ++j) {
        float4 tv = *(const float4*)(cw + (ch + j) * 4);
        cwa[j][0] = tv.x; cwa[j][1] = tv.y; cwa[j][2] = tv.z; cwa[j][3] = tv.w;
    }
    float acc[8];
#pragma unroll
    for (int j = 0; j < 8; ++j) acc[j] = cb[ch + j];
#pragma unroll
    for (int k = 0; k < 4; ++k) {
        int tt = t + k - 3;
        if (tt >= 0) {
            bf16x8 v = *(const bf16x8*)(zx + bbase + (long)tt * NPAD + DINNER + ch);
#pragma unroll
            for (int j = 0; j < 8; ++j) acc[j] += (float)v[j] * cwa[j][k];
        }
    }
    bf16x8 o;
#pragma unroll
    for (int j = 0; j < 8; ++j) o[j] = (bf16)fsilu(acc[j]);
    *(bf16x8*)(bc + (long)blt * 256 + c8 * 8) = o;
}

// ---------------- fused conv(X) + prep + stateL ----------------
__global__ __launch_bounds__(256) void k_prepL(const bf16* __restrict__ zx, const bf16* __restrict__ bc,
                                               const float* __restrict__ cw_l, const float* __restrict__ cb_l,
                                               const float* __restrict__ dt_bias_l,
                                               const float* __restrict__ Alog,
                                               float* __restrict__ Sarr, float* __restrict__ dtc,
                                               float* __restrict__ Pcb,
                                               bf16* __restrict__ XT, bf16* __restrict__ Lbuf) {
    __shared__ float S_lds[128], wl_lds[128], wtot[2];
    __shared__ bf16 Xs[136 * 64];
    __shared__ bf16 Xw[64 * 128];
    __shared__ bf16 Bt[128 * 128];
    int blk = blockIdx.x;
    int b = blk / (NHEADS * NCH);
    int r = blk % (NHEADS * NCH);
    int h = r / NCH;
    int c = r % NCH;
    int tid = threadIdx.x, lane = tid & 63, wid = tid >> 6;
    long brow0 = (long)b * SEQ + c * QCH;
#pragma unroll
    for (int i = 0; i < 5; ++i) {
        int base = i * 256 + wid * 64;
        if (base < 1048) {
            int idx = base + lane;
            long g = brow0 - 3 + (idx >> 3);
            if (g < 0) g = 0;
            if (g > (long)ROWS - 1) g = (long)ROWS - 1;
            GLD(zx + g * NPAD + DINNER + h * HEADDIM + (idx & 7) * 8,
                (char*)Xs + (long)base * 16);
        }
    }
    float ps = 0.f, dtv = 0.f;
    if (tid < 128) {
        float raw = (float)zx[(brow0 + tid) * NPAD + DINNER + CONVDIM + h] + dt_bias_l[h];
        dtv = (raw > 15.f) ? raw : log1pf(__expf(raw));
        float Ah = -__expf(Alog[h]);
        ps = dtv * Ah;
#pragma unroll
        for (int off = 1; off < 64; off <<= 1) {
            float o = __shfl_up(ps, off, 64);
            if ((tid & 63) >= off) ps += o;
        }
        if ((tid & 63) == 63) wtot[tid >> 6] = ps;
    }
    __syncthreads();
    if (tid < 128) {
        if (tid >= 64) ps += wtot[0];
        S_lds[tid] = ps;
    }
    __syncthreads();
    float Sl = S_lds[127];
    if (tid < 128) {
        wl_lds[tid] = __expf(Sl - ps) * dtv;
        Sarr[blk * QCH + tid] = ps;
        dtc[blk * QCH + tid] = dtv;
        if (tid == 127) Pcb[blk] = __expf(Sl);
    }
    __syncthreads();
    {
        int p = tid >> 2, q = tid & 3;
        float4 cwv = *(const float4*)(cw_l + (h * HEADDIM + p) * 4);
        float cbv = cb_l[h * HEADDIM + p];
        float cwa[4] = {cwv.x, cwv.y, cwv.z, cwv.w};
        char* xtb = (char*)XT + (((long)blk) << 14);
#pragma unroll
        for (int ub = 0; ub < 4; ++ub) {
            int u0 = q * 32 + ub * 8;
            bf16x8 vx, vw;
#pragma unroll
            for (int k = 0; k < 8; ++k) {
                int u = u0 + k;
                float a = cbv;
#pragma unroll
                for (int tt = 0; tt < 4; ++tt) {
                    if (c > 0 || u + tt >= 3)
                        a += (float)Xs[(u + tt) * 64 + p] * cwa[tt];
                }
                bf16 xb = (bf16)fsilu(a);
                vx[k] = xb;
                vw[k] = (bf16)((float)xb * wl_lds[u]);
            }
            long off = (long)((p * 256 + u0 * 2) ^ ((p & 7) << 4));
            *(bf16x8*)(xtb + off) = vx;
            *(bf16x8*)((char*)Xw + off) = vw;
        }
    }
#pragma unroll
    for (int nb = 0; nb < 2; ++nb) {
        __syncthreads();
#pragma unroll
        for (int i = 0; i < 4; ++i) {
            int idx = i * 256 + tid;
            GLD(bc + (brow0 + (idx >> 3)) * 256 + nb * 64 + (idx & 7) * 8,
                (char*)Xs + (i * 256 + wid * 64) * 16);
        }
        __syncthreads();
        int nl = tid >> 2, q = tid & 3;
        int n = nb * 64 + nl;
#pragma unroll
        for (int ub = 0; ub < 4; ++ub) {
            int u0 = q * 32 + ub * 8;
            bf16x8 v;
#pragma unroll
            for (int k = 0; k < 8; ++k) v[k] = Xs[(u0 + k) * 64 + nl];
            long off = (long)((n * 256 + u0 * 2) ^ ((n & 7) << 4));
            *(bf16x8*)((char*)Bt + off) = v;
        }
    }
    __syncthreads();
    f32x4 acc[4][2];
    const f32x4 vz = {0.f, 0.f, 0.f, 0.f};
#pragma unroll
    for (int mi = 0; mi < 4; ++mi)
#pragma unroll
        for (int ni = 0; ni < 2; ++ni) acc[mi][ni] = vz;
    const char* XwB = (const char*)Xw;
    const char* BtB = (const char*)Bt;
    __builtin_amdgcn_s_setprio(1);
#pragma unroll
    for (int ks = 0; ks < 4; ++ks) {
        bf16x8 af[4], bfr[2];
#pragma unroll
        for (int mi = 0; mi < 4; ++mi) {
            int pp = mi * 16 + (lane & 15);
            af[mi] = *(const bf16x8*)(XwB + ((pp * 256 + ks * 64 + (lane >> 4) * 16) ^ ((pp & 7) << 4)));
        }
#pragma unroll
        for (int ni = 0; ni < 2; ++ni) {
            int n = wid * 32 + ni * 16 + (lane & 15);
            bfr[ni] = *(const bf16x8*)(BtB + ((n * 256 + ks * 64 + (lane >> 4) * 16) ^ ((n & 7) << 4)));
        }
#pragma unroll
        for (int mi = 0; mi < 4; ++mi)
#pragma unroll
            for (int ni = 0; ni < 2; ++ni)
                acc[mi][ni] = __builtin_amdgcn_mfma_f32_16x16x32_bf16(af[mi], bfr[ni], acc[mi][ni], 0, 0, 0);
    }
    __builtin_amdgcn_s_setprio(0);
    char* lb = (char*)Lbuf + (((long)blk) << 14);
#pragma unroll
    for (int mi = 0; mi < 4; ++mi)
#pragma unroll
        for (int ni = 0; ni < 2; ++ni)
#pragma unroll
            for (int j = 0; j < 4; ++j) {
                int pp = mi * 16 + (lane >> 4) * 4 + j;
                int n = wid * 32 + ni * 16 + (lane & 15);
                *(bf16*)(lb + ((pp * 256 + n * 2) ^ ((pp & 7) << 4))) = (bf16)acc[mi][ni][j];
            }
}

// ---------------- Pass B: sequential inter-chunk combine ----------------
__global__ __launch_bounds__(256) void k_scanB(bf16* __restrict__ Lbuf, const float* __restrict__ Pc) {
    int bh = blockIdx.x >> 2;
    int q = blockIdx.x & 3;
    int off = (q * 256 + threadIdx.x) * 8;
    long base = ((long)bh * NCH) << 13;
    float s[8] = {0.f};
#pragma unroll
    for (int c = 0; c < NCH; ++c) {
        bf16* p = Lbuf + base + ((long)c << 13) + off;
        bf16x8 L = *(bf16x8*)p;
        bf16x8 I;
#pragma unroll
        for (int k = 0; k < 8; ++k) I[k] = (bf16)s[k];
        float P = Pc[bh * NCH + c];
#pragma unroll
        for (int k = 0; k < 8; ++k) s[k] = P * s[k] + (float)L[k];
        *(bf16x8*)p = I;
    }
}

// ---------------- chunk Y via MFMA -> bf16 (Cs/Bs in LDS; X/I fragments direct from global) ----------------
__global__ __launch_bounds__(512) void k_chunkY(const bf16* __restrict__ bc,
                                                const float* __restrict__ Sarr, const float* __restrict__ dtc,
                                                const float* __restrict__ Dp,
                                                const bf16* __restrict__ XT, const bf16* __restrict__ Lbuf,
                                                bf16* __restrict__ ysb) {
    __shared__ bf16 Cs[128 * 128];
    __shared__ bf16 Bs[128 * 128];
    __shared__ float S_lds[128], dt_lds[128];
    int blk = blockIdx.x;
    int b = blk / (NHEADS * NCH);
    int r = blk % (NHEADS * NCH);
    int h = r / NCH;
    int c = r % NCH;
    int tid = threadIdx.x, lane = tid & 63, wid = tid >> 6;
    long brow0 = (long)b * SEQ + c * QCH;
    const char* bcB = (const char*)bc;
#pragma unroll
    for (int i = 0; i < 4; ++i) {
        int trow = i * 32 + wid * 4 + (lane >> 4);
        int blk16 = lane & 15;
        const char* rp = bcB + (brow0 + trow) * 512;
        int sb = (blk16 ^ (trow & 7)) << 4;
        GLD(rp + 256 + sb, (char*)Cs + (i * 32 + wid * 4) * 256);
        GLD(rp + sb,       (char*)Bs + (i * 32 + wid * 4) * 256);
    }
    if (tid < 128) { S_lds[tid] = Sarr[blk * QCH + tid]; dt_lds[tid] = dtc[blk * QCH + tid]; }
    float Dh = Dp[h];
    const char* xtG = (const char*)XT + (((long)blk) << 14);
    const char* ibG = (const char*)Lbuf + (((long)blk) << 14);
    asm volatile("s_waitcnt vmcnt(0) lgkmcnt(0)" ::: "memory");
    bar_sync();
    const char* CsB = (const char*)Cs;
    char* BsB = (char*)Bs;
    const f32x4 vz = {0.f, 0.f, 0.f, 0.f};
    int wmG = wid >> 2, wnG = wid & 3;
    f32x4 accg[4][2];
#pragma unroll
    for (int mi = 0; mi < 4; ++mi)
#pragma unroll
        for (int ni = 0; ni < 2; ++ni) accg[mi][ni] = vz;
#pragma unroll
    for (int ks = 0; ks < 4; ++ks) {
        bf16x8 af[4], bfr[2];
#pragma unroll
        for (int mi = 0; mi < 4; ++mi) {
            int t = wmG * 64 + mi * 16 + (lane & 15);
            af[mi] = *(const bf16x8*)(CsB + ((t * 256 + ks * 64 + (lane >> 4) * 16) ^ ((t & 7) << 4)));
        }
#pragma unroll
        for (int ni = 0; ni < 2; ++ni) {
            int u = wnG * 32 + ni * 16 + (lane & 15);
            bfr[ni] = *(const bf16x8*)(BsB + ((u * 256 + ks * 64 + (lane >> 4) * 16) ^ ((u & 7) << 4)));
        }
#pragma unroll
        for (int mi = 0; mi < 4; ++mi)
#pragma unroll
            for (int ni = 0; ni < 2; ++ni)
                accg[mi][ni] = __builtin_amdgcn_mfma_f32_16x16x32_bf16(af[mi], bfr[ni], accg[mi][ni], 0, 0, 0);
    }
    bar_sync();
#pragma unroll
    for (int mi = 0; mi < 4; ++mi) {
#pragma unroll
        for (int j = 0; j < 4; ++j) {
            int t = wmG * 64 + mi * 16 + (lane >> 4) * 4 + j;
            float St = S_lds[t];
#pragma unroll
            for (int ni = 0; ni < 2; ++ni) {
                int u = wnG * 32 + ni * 16 + (lane & 15);
                float v = 0.f;
                if (u <= t) v = accg[mi][ni][j] * __expf(St - S_lds[u]) * dt_lds[u];
                *(bf16*)(BsB + ((t * 256 + u * 2) ^ ((t & 7) << 4))) = (bf16)v;
            }
        }
    }
    asm volatile("s_waitcnt lgkmcnt(0)" ::: "memory");
    bar_sync();
    int wmY = wid >> 1, wnY = wid & 1;
    f32x4 accy[2][2];
#pragma unroll
    for (int mi = 0; mi < 2; ++mi)
#pragma unroll
        for (int ni = 0; ni < 2; ++ni) accy[mi][ni] = vz;
#pragma unroll
    for (int ks = 0; ks < 4; ++ks) {
        bf16x8 af[2], bfr[2];
#pragma unroll
        for (int mi = 0; mi < 2; ++mi) {
            int t = wmY * 32 + mi * 16 + (lane & 15);
            af[mi] = *(const bf16x8*)(CsB + ((t * 256 + ks * 64 + (lane >> 4) * 16) ^ ((t & 7) << 4)));
        }
#pragma unroll
        for (int ni = 0; ni < 2; ++ni) {
            int pp = wnY * 32 + ni * 16 + (lane & 15);
            bfr[ni] = *(const bf16x8*)(ibG + ((pp * 256 + ks * 64 + (lane >> 4) * 16) ^ ((pp & 7) << 4)));
        }
#pragma unroll
        for (int mi = 0; mi < 2; ++mi)
#pragma unroll
            for (int ni = 0; ni < 2; ++ni)
                accy[mi][ni] = __builtin_amdgcn_mfma_f32_16x16x32_bf16(af[mi], bfr[ni], accy[mi][ni], 0, 0, 0);
    }
#pragma unroll
    for (int mi = 0; mi < 2; ++mi)
#pragma unroll
        for (int j = 0; j < 4; ++j) {
            int t = wmY * 32 + mi * 16 + (lane >> 4) * 4 + j;
            float e = __expf(S_lds[t]);
#pragma unroll
            for (int ni = 0; ni < 2; ++ni) accy[mi][ni][j] *= e;
        }
#pragma unroll
    for (int ks = 0; ks < 4; ++ks) {
        bf16x8 af[2], bfr[2];
#pragma unroll
        for (int mi = 0; mi < 2; ++mi) {
            int t = wmY * 32 + mi * 16 + (lane & 15);
            af[mi] = *(const bf16x8*)(BsB + ((t * 256 + ks * 64 + (lane >> 4) * 16) ^ ((t & 7) << 4)));
        }
#pragma unroll
        for (int ni = 0; ni < 2; ++ni) {
            int pp = wnY * 32 + ni * 16 + (lane & 15);
            bfr[ni] = *(const bf16x8*)(xtG + ((pp * 256 + ks * 64 + (lane >> 4) * 16) ^ ((pp & 7) << 4)));
        }
#pragma unroll
        for (int mi = 0; mi < 2; ++mi)
#pragma unroll
            for (int ni = 0; ni < 2; ++ni)
                accy[mi][ni] = __builtin_amdgcn_mfma_f32_16x16x32_bf16(af[mi], bfr[ni], accy[mi][ni], 0, 0, 0);
    }
#pragma unroll
    for (int mi = 0; mi < 2; ++mi)
#pragma unroll
        for (int ni = 0; ni < 2; ++ni)
#pragma unroll
            for (int j = 0; j < 4; ++j) {
                int t = wmY * 32 + mi * 16 + (lane >> 4) * 4 + j;
                int pp = wnY * 32 + ni * 16 + (lane & 15);
                float xv = (float)*(const bf16*)(xtG + ((pp * 256 + t * 2) ^ ((pp & 7) << 4)));
                ysb[(brow0 + t) * DINNER + h * HEADDIM + pp] = (bf16)(accy[mi][ni][j] + Dh * xv);
            }
}

// ---------------- gated rmsnorm (vectorized, 192 thr x bf16x8) ----------------
__global__ __launch_bounds__(192) void k_gated(const bf16* __restrict__ ys, const bf16* __restrict__ zx,
                                               const float* __restrict__ w, bf16* __restrict__ out) {
    __shared__ float sm[3];
    int r = blockIdx.x, tid = threadIdx.x;
    int d0 = tid * 8;
    bf16x8 yv = *(const bf16x8*)(ys + (long)r * DINNER + d0);
    bf16x8 zv = *(const bf16x8*)(zx + (long)r * NPAD + d0);
    float v[8]; float ss = 0.f;
#pragma unroll
    for (int j = 0; j < 8; ++j) {
        float t = (float)yv[j] * fsilu((float)zv[j]);
        v[j] = t; ss += t * t;
    }
#pragma unroll
    for (int off = 32; off; off >>= 1) ss += __shfl_down(ss, off, 64);
    if ((tid & 63) == 0) sm[tid >> 6] = ss;
    __syncthreads();
    float sc = rsqrtf((sm[0] + sm[1] + sm[2]) / (float)DINNER + EPS);
    float4 w0 = *(const float4*)(w + d0);
    float4 w1 = *(const float4*)(w + d0 + 4);
    float wa[8] = {w0.x, w0.y, w0.z, w0.w, w1.x, w1.y, w1.z, w1.w};
    bf16x8 o;
#pragma unroll
    for (int j = 0; j < 8; ++j) o[j] = (bf16)(v[j] * sc * wa[j]);
    *(bf16x8*)(out + (long)r * DINNER + d0) = o;
}

// ---------------- head: 32 rows/block, 1 atomic/block ----------------
__global__ __launch_bounds__(256) void k_head(const bf16* __restrict__ hn, const float* __restrict__ Wh,
                                              const float* __restrict__ y, float* __restrict__ out,
                                              float* __restrict__ loss) {
    __shared__ float sl[4];
    int tid = threadIdx.x, lane = tid & 63, wid = tid >> 6;
    float wv[5][12];
#pragma unroll
    for (int o = 0; o < 5; ++o)
#pragma unroll
        for (int j = 0; j < 12; ++j) wv[o][j] = Wh[o * DMODEL + lane * 12 + j];
    float lsum = 0.f;
#pragma unroll
    for (int rr = 0; rr < 8; ++rr) {
        long r = (long)blockIdx.x * 32 + wid * 8 + rr;
        const bf16* hp = hn + r * DMODEL + lane * 12;
        float hv[12];
#pragma unroll
        for (int q = 0; q < 3; ++q) {
            bf16x4 v4 = *(const bf16x4*)(hp + q * 4);
#pragma unroll
            for (int j = 0; j < 4; ++j) hv[q * 4 + j] = (float)v4[j];
        }
        float acc[5];
#pragma unroll
        for (int o = 0; o < 5; ++o) {
            float a = 0.f;
#pragma unroll
            for (int j = 0; j < 12; ++j) a += hv[j] * wv[o][j];
            acc[o] = a;
        }
#pragma unroll
        for (int o = 0; o < 5; ++o)
#pragma unroll
            for (int m = 32; m; m >>= 1) acc[o] += __shfl_xor(acc[o], m, 64);
        if (lane == 0) {
#pragma unroll
            for (int o = 0; o < 5; ++o) {
                out[r * 5 + o] = acc[o];
                float d = acc[o] - y[r * 5 + o];
                lsum += d * d;
            }
        }
    }
    if (lane == 0) sl[wid] = lsum;
    __syncthreads();
    if (tid == 0) atomicAdd(loss, (sl[0] + sl[1] + sl[2] + sl[3]) * (1.f / ((float)ROWS * 5.f)));
}

extern "C" void kernel_launch(void* const* d_in, const int* in_sizes, int n_in,
                              void* d_out, int out_size, void* d_ws, size_t ws_size,
                              hipStream_t stream) {
    const float* x      = (const float*)d_in[0];
    const float* y      = (const float*)d_in[1];
    const float* W_emb  = (const float*)d_in[2];
    const float* b_emb  = (const float*)d_in[3];
    const float* W_in   = (const float*)d_in[4];
    const float* conv_w = (const float*)d_in[5];
    const float* conv_b = (const float*)d_in[6];
    const float* dt_bias= (const float*)d_in[7];
    const float* A_log  = (const float*)d_in[8];
    const float* Dp     = (const float*)d_in[9];
    const float* norm_w = (const float*)d_in[10];
    const float* W_out  = (const float*)d_in[11];
    const float* bnw    = (const float*)d_in[12];
    const float* nfw    = (const float*)d_in[13];
    const float* W_head = (const float*)d_in[14];

    char* ws = (char*)d_ws;
    float* res  = (float*)ws;  ws += (size_t)ROWS * DMODEL * 4;
    bf16*  Lbuf = (bf16*)ws;   ws += (size_t)BATCH * NHEADS * NCH * 8192 * 2;
    bf16*  hnb  = (bf16*)ws;   ws += (size_t)ROWS * DMODEL * 2;
    bf16*  zx   = (bf16*)ws;   ws += (size_t)ROWS * NPAD * 2;
    bf16*  bc   = (bf16*)ws;   ws += (size_t)ROWS * 256 * 2;
    bf16*  ysb  = (bf16*)ws;   ws += (size_t)ROWS * DINNER * 2;
    bf16*  yfb  = (bf16*)ws;   ws += (size_t)ROWS * DINNER * 2;
    bf16*  Wib  = (bf16*)ws;   ws += (size_t)NLAYER * NPADW * DMODEL * 2;
    bf16*  Wob  = (bf16*)ws;   ws += (size_t)NLAYER * DMODEL * DINNER * 2;
    float* Pcb  = (float*)ws;  ws += (size_t)BATCH * NHEADS * NCH * 4;
    float* Sarr = (float*)ws;  ws += (size_t)BATCH * NHEADS * NCH * QCH * 4;
    float* dtc  = (float*)ws;  ws += (size_t)BATCH * NHEADS * NCH * QCH * 4;
    bf16*  XT   = (bf16*)ws;   ws += (size_t)BATCH * NHEADS * NCH * 8192 * 2;

    float* out_p  = (float*)d_out;
    float* loss_p = out_p + (size_t)ROWS * 5;

    hipMemsetAsync(loss_p, 0, 4, stream);
    k_embed<<<ROWS * (DMODEL / 4) / 256, 256, 0, stream>>>(x, W_emb, b_emb, res);
    k_cvt_in<<<NLAYER * NPADW * DMODEL / 4 / 256, 256, 0, stream>>>(W_in, Wib);
    k_cvt_out<<<NLAYER * DMODEL * DINNER / 4 / 256, 256, 0, stream>>>(W_out, Wob);

    const int NBHC = BATCH * NHEADS * NCH;   // 1536
    for (int l = 0; l < NLAYER; ++l) {
        const float* cw_l = conv_w + (size_t)l * CONVDIM * 4;
        const float* cb_l = conv_b + (size_t)l * CONVDIM;
        k_rmsnorm<<<ROWS, 192, 0, stream>>>(res, bnw + l * DMODEL, hnb);
        dim3 g1(ROWS / 256, NPADW / 256);
        k_gemm<bf16, 256, 256, 32, 512, false><<<g1, 512, 0, stream>>>(hnb, Wib + (size_t)l * NPADW * DMODEL, zx, DMODEL, NPAD, NPAD);
        k_convBC<<<ROWS * 32 / 256, 256, 0, stream>>>(zx, cw_l, cb_l, bc);
        k_prepL<<<NBHC, 256, 0, stream>>>(zx, bc, cw_l, cb_l, dt_bias + l * NHEADS, A_log + l * NHEADS,
                                          Sarr, dtc, Pcb, XT, Lbuf);
        k_scanB<<<BATCH * NHEADS * 4, 256, 0, stream>>>(Lbuf, Pcb);
        k_chunkY<<<NBHC, 512, 0, stream>>>(bc, Sarr, dtc, Dp + l * NHEADS, XT, Lbuf, ysb);
        k_gated<<<ROWS, 192, 0, stream>>>(ysb, zx, norm_w + l * DINNER, yfb);
        dim3 g2(ROWS / 128, DMODEL / 64);
        k_gemm<float, 128, 64, 64, 256, true><<<g2, 256, 0, stream>>>(yfb, Wob + (size_t)l * DMODEL * DINNER, res, DINNER, DMODEL, DMODEL);
    }

    k_rmsnorm<<<ROWS, 192, 0, stream>>>(res, nfw, hnb);
    k_head<<<256, 256, 0, stream>>>(hnb, W_head, y, out_p, loss_p);
}

// Round 14
// 1666.243 us; speedup vs baseline: 1.0296x; 1.0296x over previous
//
#include <hip/hip_runtime.h>
#include <hip/hip_bf16.h>
#include <math.h>

#define BATCH 4
#define SEQ 2048
#define DMODEL 768
#define NLAYER 8
#define DINNER 1536
#define HEADDIM 64
#define NHEADS 24
#define DSTATE 128
#define CONVDIM 1792
#define DINPROJ 3352
#define NPAD 3456
#define NPADW 3584
#define ROWS (BATCH*SEQ)
#define EPS 1e-5f
#define QCH 128
#define NCH (SEQ/QCH)

typedef __bf16 bf16;
typedef bf16 bf16x8 __attribute__((ext_vector_type(8)));
typedef bf16 bf16x4 __attribute__((ext_vector_type(4)));
typedef float f32x4 __attribute__((ext_vector_type(4)));

#define GLD(src, dst) __builtin_amdgcn_global_load_lds( \
    (const __attribute__((address_space(1))) void*)(src), \
    (__attribute__((address_space(3))) void*)(dst), 16, 0, 0)

__device__ __forceinline__ void bar_sync() {
    asm volatile("" ::: "memory");
    __builtin_amdgcn_s_barrier();
    asm volatile("" ::: "memory");
}

__device__ __forceinline__ float fsilu(float x) { return x / (1.f + __expf(-x)); }

// ---------------- embed: res = x @ W_emb^T + b_emb (4 outputs/thread) ----------------
__global__ void k_embed(const float* __restrict__ x, const float* __restrict__ We,
                        const float* __restrict__ be, float* __restrict__ res) {
    int idx = blockIdx.x * 256 + threadIdx.x;          // ROWS * DMODEL/4
    int d0 = (idx % (DMODEL / 4)) * 4;
    int bl = idx / (DMODEL / 4);
    float xv[6];
#pragma unroll
    for (int i = 0; i < 6; ++i) xv[i] = x[bl * 6 + i];
    float4 o;
    float* op = &o.x;
#pragma unroll
    for (int j = 0; j < 4; ++j) {
        float acc = be[d0 + j];
#pragma unroll
        for (int i = 0; i < 6; ++i) acc += xv[i] * We[(d0 + j) * 6 + i];
        op[j] = acc;
    }
    *(float4*)(res + (long)bl * DMODEL + d0) = o;
}

// ---------------- read-only rmsnorm (vectorized, 192 thr x float4) ----------------
__global__ __launch_bounds__(192) void k_rmsnorm(const float* __restrict__ res,
                                                 const float* __restrict__ w,
                                                 bf16* __restrict__ out) {
    __shared__ float sm[3];
    int r = blockIdx.x, tid = threadIdx.x;
    int d0 = tid * 4;
    float4 v = *(const float4*)(res + (long)r * DMODEL + d0);
    float ss = v.x * v.x + v.y * v.y + v.z * v.z + v.w * v.w;
#pragma unroll
    for (int off = 32; off; off >>= 1) ss += __shfl_down(ss, off, 64);
    if ((tid & 63) == 0) sm[tid >> 6] = ss;
    __syncthreads();
    float sc = rsqrtf((sm[0] + sm[1] + sm[2]) / (float)DMODEL + EPS);
    float4 wv = *(const float4*)(w + d0);
    bf16x4 o;
    o[0] = (bf16)(v.x * sc * wv.x);
    o[1] = (bf16)(v.y * sc * wv.y);
    o[2] = (bf16)(v.z * sc * wv.z);
    o[3] = (bf16)(v.w * sc * wv.w);
    *(bf16x4*)(out + (long)r * DMODEL + d0) = o;
}

// ---------------- batched weight conversions (vectorized x4) ----------------
__global__ void k_cvt_in(const float* __restrict__ src, bf16* __restrict__ dst) {
    long e = ((long)blockIdx.x * 256 + threadIdx.x) * 4;   // NLAYER*NPADW*DMODEL elems
    int l = (int)(e / (NPADW * DMODEL));
    long rem = e % (NPADW * DMODEL);
    int n = (int)(rem / DMODEL);
    int d = (int)(rem % DMODEL);
    bf16x4 o;
    if (n < DINPROJ) {
        float4 v = *(const float4*)(src + ((long)l * DINPROJ + n) * DMODEL + d);
        o[0] = (bf16)v.x; o[1] = (bf16)v.y; o[2] = (bf16)v.z; o[3] = (bf16)v.w;
    } else {
        o[0] = (bf16)0.f; o[1] = (bf16)0.f; o[2] = (bf16)0.f; o[3] = (bf16)0.f;
    }
    *(bf16x4*)(dst + e) = o;
}
__global__ void k_cvt_out(const float* __restrict__ src, bf16* __restrict__ dst) {
    long e = ((long)blockIdx.x * 256 + threadIdx.x) * 4;
    float4 v = *(const float4*)(src + e);
    bf16x4 o;
    o[0] = (bf16)v.x; o[1] = (bf16)v.y; o[2] = (bf16)v.z; o[3] = (bf16)v.w;
    *(bf16x4*)(dst + e) = o;
}

// ---------------- bf16 MFMA GEMM: C[M,N] (=|+=) A[M,K] @ B[N,K]^T ----------------
// BMxBN tile, BK=64, counted-vmcnt depth-2 pipeline, XOR-swizzled LDS.
template <typename OT, int BM, int BN, int TH, bool ACC>
__global__ __launch_bounds__(TH) void k_gemm(const bf16* __restrict__ A, const bf16* __restrict__ B,
                                             OT* __restrict__ C, int K, int ldc, int Nact) {
    constexpr int NW  = TH / 64;
    constexpr int nWn = (BN / 64 < 4) ? BN / 64 : 4;
    constexpr int nWm = NW / nWn;
    constexpr int WMR = BM / nWm;
    constexpr int MI  = WMR / 16;
    constexpr int MH  = MI / 2;
    constexpr int NI  = 4;
    constexpr int RG  = TH / 8;
    constexpr int AG  = BM / RG;
    constexpr int BG  = BN / RG;
    __shared__ bf16 As[2][BM * 64];
    __shared__ bf16 Bs[2][BN * 64];
    const int tid = threadIdx.x;
    const int lane = tid & 63;
    const int w = tid >> 6;
    const int wm = w / nWn, wn = w % nWn;
    const long rowA0 = (long)blockIdx.x * BM;
    const long rowB0 = (long)blockIdx.y * BN;
    const int srow = tid >> 3;
    const int scol = ((tid & 7) ^ (srow & 7)) * 8;
    const bf16* Ab = A + rowA0 * K + scol;
    const bf16* Bb = B + rowB0 * K + scol;

    f32x4 acc[MI][NI];
    const f32x4 vz = {0.f, 0.f, 0.f, 0.f};
#pragma unroll
    for (int mi = 0; mi < MI; ++mi)
#pragma unroll
        for (int ni = 0; ni < NI; ++ni) acc[mi][ni] = vz;

    auto stage = [&](int buf, int kt) {
#pragma unroll
        for (int j = 0; j < AG; ++j)
            GLD(Ab + (long)(j * RG + srow) * K + kt, &As[buf][(j * TH + w * 64) * 8]);
#pragma unroll
        for (int j = 0; j < BG; ++j)
            GLD(Bb + (long)(j * RG + srow) * K + kt, &Bs[buf][(j * TH + w * 64) * 8]);
    };
    auto waitv = [&]() {
        if constexpr (AG + BG == 8) asm volatile("s_waitcnt vmcnt(8)" ::: "memory");
        else                        asm volatile("s_waitcnt vmcnt(6)" ::: "memory");
    };

    bf16x8 bfr[NI][2];
    bf16x8 af[MH][2];
    auto rd_bfr = [&](int buf) {
        const char* BsB = (const char*)Bs[buf];
#pragma unroll
        for (int ni = 0; ni < NI; ++ni)
#pragma unroll
            for (int ks = 0; ks < 2; ++ks) {
                int r = wn * 64 + ni * 16 + (lane & 15);
                bfr[ni][ks] = *(const bf16x8*)(BsB + r * 128 + ((ks * 64 + (lane >> 4) * 16) ^ ((r & 7) << 4)));
            }
    };
    auto rd_af = [&](int buf, int m0) {
        const char* AsB = (const char*)As[buf];
#pragma unroll
        for (int mi = 0; mi < MH; ++mi)
#pragma unroll
            for (int ks = 0; ks < 2; ++ks) {
                int r = wm * WMR + (m0 + mi) * 16 + (lane & 15);
                af[mi][ks] = *(const bf16x8*)(AsB + r * 128 + ((ks * 64 + (lane >> 4) * 16) ^ ((r & 7) << 4)));
            }
    };
    auto do_half = [&](int m0) {
#pragma unroll
        for (int mi = 0; mi < MH; ++mi)
#pragma unroll
            for (int ni = 0; ni < NI; ++ni)
#pragma unroll
                for (int ks = 0; ks < 2; ++ks)
                    acc[m0 + mi][ni] = __builtin_amdgcn_mfma_f32_16x16x32_bf16(af[mi][ks], bfr[ni][ks], acc[m0 + mi][ni], 0, 0, 0);
    };

    const int NT = K / 64;
    stage(0, 0);
    stage(1, 64);
    for (int t = 0; t < NT - 2; ++t) {
        waitv();
        bar_sync();
        rd_bfr(t & 1);
        rd_af(t & 1, 0);
        do_half(0);
        rd_af(t & 1, MH);
        asm volatile("s_waitcnt lgkmcnt(0)" ::: "memory");
        bar_sync();
        stage(t & 1, (t + 2) * 64);
        __builtin_amdgcn_sched_barrier(0);
        do_half(MH);
    }
    {
        waitv();
        bar_sync();
        rd_bfr((NT - 2) & 1);
        rd_af((NT - 2) & 1, 0);
        do_half(0);
        rd_af((NT - 2) & 1, MH);
        do_half(MH);
    }
    {
        asm volatile("s_waitcnt vmcnt(0)" ::: "memory");
        bar_sync();
        rd_bfr((NT - 1) & 1);
        rd_af((NT - 1) & 1, 0);
        do_half(0);
        rd_af((NT - 1) & 1, MH);
        do_half(MH);
    }

    const int crow = (lane >> 4) * 4;
    const int ccol = lane & 15;
#pragma unroll
    for (int mi = 0; mi < MI; ++mi)
#pragma unroll
        for (int ni = 0; ni < NI; ++ni) {
            long r0 = rowA0 + wm * WMR + mi * 16 + crow;
            long c0 = rowB0 + wn * 64 + ni * 16 + ccol;
            if ((int)c0 < Nact) {
#pragma unroll
                for (int j = 0; j < 4; ++j) {
                    if constexpr (ACC) C[(r0 + j) * ldc + c0] += (OT)acc[mi][ni][j];
                    else               C[(r0 + j) * ldc + c0]  = (OT)acc[mi][ni][j];
                }
            }
        }
}

// ---------------- slim conv for B/C channels only -> bc[ROWS][256] ----------------
__global__ void k_convBC(const bf16* __restrict__ zx, const float* __restrict__ cw,
                         const float* __restrict__ cb, bf16* __restrict__ bc) {
    int idx = blockIdx.x * 256 + threadIdx.x;   // ROWS * 32
    int c8 = idx & 31; int blt = idx >> 5;
    int t = blt % SEQ;
    int ch = DINNER + c8 * 8;
    long bbase = (long)(blt - t) * NPAD;
    float cwa[8][4];
#pragma unroll
    for (int j = 0; j < 8; ++j) {
        float4 tv = *(const float4*)(cw + (ch + j) * 4);
        cwa[j][0] = tv.x; cwa[j][1] = tv.y; cwa[j][2] = tv.z; cwa[j][3] = tv.w;
    }
    float acc[8];
#pragma unroll
    for (int j = 0; j < 8; ++j) acc[j] = cb[ch + j];
#pragma unroll
    for (int k = 0; k < 4; ++k) {
        int tt = t + k - 3;
        if (tt >= 0) {
            bf16x8 v = *(const bf16x8*)(zx + bbase + (long)tt * NPAD + DINNER + ch);
#pragma unroll
            for (int j = 0; j < 8; ++j) acc[j] += (float)v[j] * cwa[j][k];
        }
    }
    bf16x8 o;
#pragma unroll
    for (int j = 0; j < 8; ++j) o[j] = (bf16)fsilu(acc[j]);
    *(bf16x8*)(bc + (long)blt * 256 + c8 * 8) = o;
}

// ---------------- fused conv(X) + prep + stateL ----------------
__global__ __launch_bounds__(256) void k_prepL(const bf16* __restrict__ zx, const bf16* __restrict__ bc,
                                               const float* __restrict__ cw_l, const float* __restrict__ cb_l,
                                               const float* __restrict__ dt_bias_l,
                                               const float* __restrict__ Alog,
                                               float* __restrict__ Sarr, float* __restrict__ dtc,
                                               float* __restrict__ Pcb,
                                               bf16* __restrict__ XT, bf16* __restrict__ Lbuf) {
    __shared__ float S_lds[128], wl_lds[128], wtot[2];
    __shared__ bf16 Xs[136 * 64];
    __shared__ bf16 Xw[64 * 128];
    __shared__ bf16 Bt[128 * 128];
    int blk = blockIdx.x;
    int b = blk / (NHEADS * NCH);
    int r = blk % (NHEADS * NCH);
    int h = r / NCH;
    int c = r % NCH;
    int tid = threadIdx.x, lane = tid & 63, wid = tid >> 6;
    long brow0 = (long)b * SEQ + c * QCH;
#pragma unroll
    for (int i = 0; i < 5; ++i) {
        int base = i * 256 + wid * 64;
        if (base < 1048) {
            int idx = base + lane;
            long g = brow0 - 3 + (idx >> 3);
            if (g < 0) g = 0;
            if (g > (long)ROWS - 1) g = (long)ROWS - 1;
            GLD(zx + g * NPAD + DINNER + h * HEADDIM + (idx & 7) * 8,
                (char*)Xs + (long)base * 16);
        }
    }
    float ps = 0.f, dtv = 0.f;
    if (tid < 128) {
        float raw = (float)zx[(brow0 + tid) * NPAD + DINNER + CONVDIM + h] + dt_bias_l[h];
        dtv = (raw > 15.f) ? raw : log1pf(__expf(raw));
        float Ah = -__expf(Alog[h]);
        ps = dtv * Ah;
#pragma unroll
        for (int off = 1; off < 64; off <<= 1) {
            float o = __shfl_up(ps, off, 64);
            if ((tid & 63) >= off) ps += o;
        }
        if ((tid & 63) == 63) wtot[tid >> 6] = ps;
    }
    __syncthreads();
    if (tid < 128) {
        if (tid >= 64) ps += wtot[0];
        S_lds[tid] = ps;
    }
    __syncthreads();
    float Sl = S_lds[127];
    if (tid < 128) {
        wl_lds[tid] = __expf(Sl - ps) * dtv;
        Sarr[blk * QCH + tid] = ps;
        dtc[blk * QCH + tid] = dtv;
        if (tid == 127) Pcb[blk] = __expf(Sl);
    }
    __syncthreads();
    {
        int p = tid >> 2, q = tid & 3;
        float4 cwv = *(const float4*)(cw_l + (h * HEADDIM + p) * 4);
        float cbv = cb_l[h * HEADDIM + p];
        float cwa[4] = {cwv.x, cwv.y, cwv.z, cwv.w};
        char* xtb = (char*)XT + (((long)blk) << 14);
#pragma unroll
        for (int ub = 0; ub < 4; ++ub) {
            int u0 = q * 32 + ub * 8;
            bf16x8 vx, vw;
#pragma unroll
            for (int k = 0; k < 8; ++k) {
                int u = u0 + k;
                float a = cbv;
#pragma unroll
                for (int tt = 0; tt < 4; ++tt) {
                    if (c > 0 || u + tt >= 3)
                        a += (float)Xs[(u + tt) * 64 + p] * cwa[tt];
                }
                bf16 xb = (bf16)fsilu(a);
                vx[k] = xb;
                vw[k] = (bf16)((float)xb * wl_lds[u]);
            }
            long off = (long)((p * 256 + u0 * 2) ^ ((p & 7) << 4));
            *(bf16x8*)(xtb + off) = vx;
            *(bf16x8*)((char*)Xw + off) = vw;
        }
    }
#pragma unroll
    for (int nb = 0; nb < 2; ++nb) {
        __syncthreads();
#pragma unroll
        for (int i = 0; i < 4; ++i) {
            int idx = i * 256 + tid;
            GLD(bc + (brow0 + (idx >> 3)) * 256 + nb * 64 + (idx & 7) * 8,
                (char*)Xs + (i * 256 + wid * 64) * 16);
        }
        __syncthreads();
        int nl = tid >> 2, q = tid & 3;
        int n = nb * 64 + nl;
#pragma unroll
        for (int ub = 0; ub < 4; ++ub) {
            int u0 = q * 32 + ub * 8;
            bf16x8 v;
#pragma unroll
            for (int k = 0; k < 8; ++k) v[k] = Xs[(u0 + k) * 64 + nl];
            long off = (long)((n * 256 + u0 * 2) ^ ((n & 7) << 4));
            *(bf16x8*)((char*)Bt + off) = v;
        }
    }
    __syncthreads();
    f32x4 acc[4][2];
    const f32x4 vz = {0.f, 0.f, 0.f, 0.f};
#pragma unroll
    for (int mi = 0; mi < 4; ++mi)
#pragma unroll
        for (int ni = 0; ni < 2; ++ni) acc[mi][ni] = vz;
    const char* XwB = (const char*)Xw;
    const char* BtB = (const char*)Bt;
    __builtin_amdgcn_s_setprio(1);
#pragma unroll
    for (int ks = 0; ks < 4; ++ks) {
        bf16x8 af[4], bfr[2];
#pragma unroll
        for (int mi = 0; mi < 4; ++mi) {
            int pp = mi * 16 + (lane & 15);
            af[mi] = *(const bf16x8*)(XwB + ((pp * 256 + ks * 64 + (lane >> 4) * 16) ^ ((pp & 7) << 4)));
        }
#pragma unroll
        for (int ni = 0; ni < 2; ++ni) {
            int n = wid * 32 + ni * 16 + (lane & 15);
            bfr[ni] = *(const bf16x8*)(BtB + ((n * 256 + ks * 64 + (lane >> 4) * 16) ^ ((n & 7) << 4)));
        }
#pragma unroll
        for (int mi = 0; mi < 4; ++mi)
#pragma unroll
            for (int ni = 0; ni < 2; ++ni)
                acc[mi][ni] = __builtin_amdgcn_mfma_f32_16x16x32_bf16(af[mi], bfr[ni], acc[mi][ni], 0, 0, 0);
    }
    __builtin_amdgcn_s_setprio(0);
    char* lb = (char*)Lbuf + (((long)blk) << 14);
#pragma unroll
    for (int mi = 0; mi < 4; ++mi)
#pragma unroll
        for (int ni = 0; ni < 2; ++ni)
#pragma unroll
            for (int j = 0; j < 4; ++j) {
                int pp = mi * 16 + (lane >> 4) * 4 + j;
                int n = wid * 32 + ni * 16 + (lane & 15);
                *(bf16*)(lb + ((pp * 256 + n * 2) ^ ((pp & 7) << 4))) = (bf16)acc[mi][ni][j];
            }
}

// ---------------- Pass B: sequential inter-chunk combine ----------------
__global__ __launch_bounds__(256) void k_scanB(bf16* __restrict__ Lbuf, const float* __restrict__ Pc) {
    int bh = blockIdx.x >> 2;
    int q = blockIdx.x & 3;
    int off = (q * 256 + threadIdx.x) * 8;
    long base = ((long)bh * NCH) << 13;
    float s[8] = {0.f};
#pragma unroll
    for (int c = 0; c < NCH; ++c) {
        bf16* p = Lbuf + base + ((long)c << 13) + off;
        bf16x8 L = *(bf16x8*)p;
        bf16x8 I;
#pragma unroll
        for (int k = 0; k < 8; ++k) I[k] = (bf16)s[k];
        float P = Pc[bh * NCH + c];
#pragma unroll
        for (int k = 0; k < 8; ++k) s[k] = P * s[k] + (float)L[k];
        *(bf16x8*)p = I;
    }
}

// ---------------- chunk Y via MFMA -> bf16 (Cs/Bs in LDS; X/I fragments direct from global) ----------------
__global__ __launch_bounds__(512) void k_chunkY(const bf16* __restrict__ bc,
                                                const float* __restrict__ Sarr, const float* __restrict__ dtc,
                                                const float* __restrict__ Dp,
                                                const bf16* __restrict__ XT, const bf16* __restrict__ Lbuf,
                                                bf16* __restrict__ ysb) {
    __shared__ bf16 Cs[128 * 128];
    __shared__ bf16 Bs[128 * 128];
    __shared__ float S_lds[128], dt_lds[128];
    int blk = blockIdx.x;
    int b = blk / (NHEADS * NCH);
    int r = blk % (NHEADS * NCH);
    int h = r / NCH;
    int c = r % NCH;
    int tid = threadIdx.x, lane = tid & 63, wid = tid >> 6;
    long brow0 = (long)b * SEQ + c * QCH;
    const char* bcB = (const char*)bc;
#pragma unroll
    for (int i = 0; i < 4; ++i) {
        int trow = i * 32 + wid * 4 + (lane >> 4);
        int blk16 = lane & 15;
        const char* rp = bcB + (brow0 + trow) * 512;
        int sb = (blk16 ^ (trow & 7)) << 4;
        GLD(rp + 256 + sb, (char*)Cs + (i * 32 + wid * 4) * 256);
        GLD(rp + sb,       (char*)Bs + (i * 32 + wid * 4) * 256);
    }
    if (tid < 128) { S_lds[tid] = Sarr[blk * QCH + tid]; dt_lds[tid] = dtc[blk * QCH + tid]; }
    float Dh = Dp[h];
    const char* xtG = (const char*)XT + (((long)blk) << 14);
    const char* ibG = (const char*)Lbuf + (((long)blk) << 14);
    asm volatile("s_waitcnt vmcnt(0) lgkmcnt(0)" ::: "memory");
    bar_sync();
    const char* CsB = (const char*)Cs;
    char* BsB = (char*)Bs;
    const f32x4 vz = {0.f, 0.f, 0.f, 0.f};
    int wmG = wid >> 2, wnG = wid & 3;
    f32x4 accg[4][2];
#pragma unroll
    for (int mi = 0; mi < 4; ++mi)
#pragma unroll
        for (int ni = 0; ni < 2; ++ni) accg[mi][ni] = vz;
#pragma unroll
    for (int ks = 0; ks < 4; ++ks) {
        bf16x8 af[4], bfr[2];
#pragma unroll
        for (int mi = 0; mi < 4; ++mi) {
            int t = wmG * 64 + mi * 16 + (lane & 15);
            af[mi] = *(const bf16x8*)(CsB + ((t * 256 + ks * 64 + (lane >> 4) * 16) ^ ((t & 7) << 4)));
        }
#pragma unroll
        for (int ni = 0; ni < 2; ++ni) {
            int u = wnG * 32 + ni * 16 + (lane & 15);
            bfr[ni] = *(const bf16x8*)(BsB + ((u * 256 + ks * 64 + (lane >> 4) * 16) ^ ((u & 7) << 4)));
        }
#pragma unroll
        for (int mi = 0; mi < 4; ++mi)
#pragma unroll
            for (int ni = 0; ni < 2; ++ni)
                accg[mi][ni] = __builtin_amdgcn_mfma_f32_16x16x32_bf16(af[mi], bfr[ni], accg[mi][ni], 0, 0, 0);
    }
    bar_sync();
#pragma unroll
    for (int mi = 0; mi < 4; ++mi) {
#pragma unroll
        for (int j = 0; j < 4; ++j) {
            int t = wmG * 64 + mi * 16 + (lane >> 4) * 4 + j;
            float St = S_lds[t];
#pragma unroll
            for (int ni = 0; ni < 2; ++ni) {
                int u = wnG * 32 + ni * 16 + (lane & 15);
                float v = 0.f;
                if (u <= t) v = accg[mi][ni][j] * __expf(St - S_lds[u]) * dt_lds[u];
                *(bf16*)(BsB + ((t * 256 + u * 2) ^ ((t & 7) << 4))) = (bf16)v;
            }
        }
    }
    asm volatile("s_waitcnt lgkmcnt(0)" ::: "memory");
    bar_sync();
    int wmY = wid >> 1, wnY = wid & 1;
    f32x4 accy[2][2];
#pragma unroll
    for (int mi = 0; mi < 2; ++mi)
#pragma unroll
        for (int ni = 0; ni < 2; ++ni) accy[mi][ni] = vz;
#pragma unroll
    for (int ks = 0; ks < 4; ++ks) {
        bf16x8 af[2], bfr[2];
#pragma unroll
        for (int mi = 0; mi < 2; ++mi) {
            int t = wmY * 32 + mi * 16 + (lane & 15);
            af[mi] = *(const bf16x8*)(CsB + ((t * 256 + ks * 64 + (lane >> 4) * 16) ^ ((t & 7) << 4)));
        }
#pragma unroll
        for (int ni = 0; ni < 2; ++ni) {
            int pp = wnY * 32 + ni * 16 + (lane & 15);
            bfr[ni] = *(const bf16x8*)(ibG + ((pp * 256 + ks * 64 + (lane >> 4) * 16) ^ ((pp & 7) << 4)));
        }
#pragma unroll
        for (int mi = 0; mi < 2; ++mi)
#pragma unroll
            for (int ni = 0; ni < 2; ++ni)
                accy[mi][ni] = __builtin_amdgcn_mfma_f32_16x16x32_bf16(af[mi], bfr[ni], accy[mi][ni], 0, 0, 0);
    }
#pragma unroll
    for (int mi = 0; mi < 2; ++mi)
#pragma unroll
        for (int j = 0; j < 4; ++j) {
            int t = wmY * 32 + mi * 16 + (lane >> 4) * 4 + j;
            float e = __expf(S_lds[t]);
#pragma unroll
            for (int ni = 0; ni < 2; ++ni) accy[mi][ni][j] *= e;
        }
#pragma unroll
    for (int ks = 0; ks < 4; ++ks) {
        bf16x8 af[2], bfr[2];
#pragma unroll
        for (int mi = 0; mi < 2; ++mi) {
            int t = wmY * 32 + mi * 16 + (lane & 15);
            af[mi] = *(const bf16x8*)(BsB + ((t * 256 + ks * 64 + (lane >> 4) * 16) ^ ((t & 7) << 4)));
        }
#pragma unroll
        for (int ni = 0; ni < 2; ++ni) {
            int pp = wnY * 32 + ni * 16 + (lane & 15);
            bfr[ni] = *(const bf16x8*)(xtG + ((pp * 256 + ks * 64 + (lane >> 4) * 16) ^ ((pp & 7) << 4)));
        }
#pragma unroll
        for (int mi = 0; mi < 2; ++mi)
#pragma unroll
            for (int ni = 0; ni < 2; ++ni)
                accy[mi][ni] = __builtin_amdgcn_mfma_f32_16x16x32_bf16(af[mi], bfr[ni], accy[mi][ni], 0, 0, 0);
    }
#pragma unroll
    for (int mi = 0; mi < 2; ++mi)
#pragma unroll
        for (int ni = 0; ni < 2; ++ni)
#pragma unroll
            for (int j = 0; j < 4; ++j) {
                int t = wmY * 32 + mi * 16 + (lane >> 4) * 4 + j;
                int pp = wnY * 32 + ni * 16 + (lane & 15);
                float xv = (float)*(const bf16*)(xtG + ((pp * 256 + t * 2) ^ ((pp & 7) << 4)));
                ysb[(brow0 + t) * DINNER + h * HEADDIM + pp] = (bf16)(accy[mi][ni][j] + Dh * xv);
            }
}

// ---------------- gated rmsnorm (vectorized, 192 thr x bf16x8) ----------------
__global__ __launch_bounds__(192) void k_gated(const bf16* __restrict__ ys, const bf16* __restrict__ zx,
                                               const float* __restrict__ w, bf16* __restrict__ out) {
    __shared__ float sm[3];
    int r = blockIdx.x, tid = threadIdx.x;
    int d0 = tid * 8;
    bf16x8 yv = *(const bf16x8*)(ys + (long)r * DINNER + d0);
    bf16x8 zv = *(const bf16x8*)(zx + (long)r * NPAD + d0);
    float v[8]; float ss = 0.f;
#pragma unroll
    for (int j = 0; j < 8; ++j) {
        float t = (float)yv[j] * fsilu((float)zv[j]);
        v[j] = t; ss += t * t;
    }
#pragma unroll
    for (int off = 32; off; off >>= 1) ss += __shfl_down(ss, off, 64);
    if ((tid & 63) == 0) sm[tid >> 6] = ss;
    __syncthreads();
    float sc = rsqrtf((sm[0] + sm[1] + sm[2]) / (float)DINNER + EPS);
    float4 w0 = *(const float4*)(w + d0);
    float4 w1 = *(const float4*)(w + d0 + 4);
    float wa[8] = {w0.x, w0.y, w0.z, w0.w, w1.x, w1.y, w1.z, w1.w};
    bf16x8 o;
#pragma unroll
    for (int j = 0; j < 8; ++j) o[j] = (bf16)(v[j] * sc * wa[j]);
    *(bf16x8*)(out + (long)r * DINNER + d0) = o;
}

// ---------------- head: 32 rows/block, 1 atomic/block ----------------
__global__ __launch_bounds__(256) void k_head(const bf16* __restrict__ hn, const float* __restrict__ Wh,
                                              const float* __restrict__ y, float* __restrict__ out,
                                              float* __restrict__ loss) {
    __shared__ float sl[4];
    int tid = threadIdx.x, lane = tid & 63, wid = tid >> 6;
    float wv[5][12];
#pragma unroll
    for (int o = 0; o < 5; ++o)
#pragma unroll
        for (int j = 0; j < 12; ++j) wv[o][j] = Wh[o * DMODEL + lane * 12 + j];
    float lsum = 0.f;
#pragma unroll
    for (int rr = 0; rr < 8; ++rr) {
        long r = (long)blockIdx.x * 32 + wid * 8 + rr;
        const bf16* hp = hn + r * DMODEL + lane * 12;
        float hv[12];
#pragma unroll
        for (int q = 0; q < 3; ++q) {
            bf16x4 v4 = *(const bf16x4*)(hp + q * 4);
#pragma unroll
            for (int j = 0; j < 4; ++j) hv[q * 4 + j] = (float)v4[j];
        }
        float acc[5];
#pragma unroll
        for (int o = 0; o < 5; ++o) {
            float a = 0.f;
#pragma unroll
            for (int j = 0; j < 12; ++j) a += hv[j] * wv[o][j];
            acc[o] = a;
        }
#pragma unroll
        for (int o = 0; o < 5; ++o)
#pragma unroll
            for (int m = 32; m; m >>= 1) acc[o] += __shfl_xor(acc[o], m, 64);
        if (lane == 0) {
#pragma unroll
            for (int o = 0; o < 5; ++o) {
                out[r * 5 + o] = acc[o];
                float d = acc[o] - y[r * 5 + o];
                lsum += d * d;
            }
        }
    }
    if (lane == 0) sl[wid] = lsum;
    __syncthreads();
    if (tid == 0) atomicAdd(loss, (sl[0] + sl[1] + sl[2] + sl[3]) * (1.f / ((float)ROWS * 5.f)));
}

extern "C" void kernel_launch(void* const* d_in, const int* in_sizes, int n_in,
                              void* d_out, int out_size, void* d_ws, size_t ws_size,
                              hipStream_t stream) {
    const float* x      = (const float*)d_in[0];
    const float* y      = (const float*)d_in[1];
    const float* W_emb  = (const float*)d_in[2];
    const float* b_emb  = (const float*)d_in[3];
    const float* W_in   = (const float*)d_in[4];
    const float* conv_w = (const float*)d_in[5];
    const float* conv_b = (const float*)d_in[6];
    const float* dt_bias= (const float*)d_in[7];
    const float* A_log  = (const float*)d_in[8];
    const float* Dp     = (const float*)d_in[9];
    const float* norm_w = (const float*)d_in[10];
    const float* W_out  = (const float*)d_in[11];
    const float* bnw    = (const float*)d_in[12];
    const float* nfw    = (const float*)d_in[13];
    const float* W_head = (const float*)d_in[14];

    char* ws = (char*)d_ws;
    float* res  = (float*)ws;  ws += (size_t)ROWS * DMODEL * 4;
    bf16*  Lbuf = (bf16*)ws;   ws += (size_t)BATCH * NHEADS * NCH * 8192 * 2;
    bf16*  hnb  = (bf16*)ws;   ws += (size_t)ROWS * DMODEL * 2;
    bf16*  zx   = (bf16*)ws;   ws += (size_t)ROWS * NPAD * 2;
    bf16*  bc   = (bf16*)ws;   ws += (size_t)ROWS * 256 * 2;
    bf16*  ysb  = (bf16*)ws;   ws += (size_t)ROWS * DINNER * 2;
    bf16*  yfb  = (bf16*)ws;   ws += (size_t)ROWS * DINNER * 2;
    bf16*  Wib  = (bf16*)ws;   ws += (size_t)NLAYER * NPADW * DMODEL * 2;
    bf16*  Wob  = (bf16*)ws;   ws += (size_t)NLAYER * DMODEL * DINNER * 2;
    float* Pcb  = (float*)ws;  ws += (size_t)BATCH * NHEADS * NCH * 4;
    float* Sarr = (float*)ws;  ws += (size_t)BATCH * NHEADS * NCH * QCH * 4;
    float* dtc  = (float*)ws;  ws += (size_t)BATCH * NHEADS * NCH * QCH * 4;
    bf16*  XT   = (bf16*)ws;   ws += (size_t)BATCH * NHEADS * NCH * 8192 * 2;

    float* out_p  = (float*)d_out;
    float* loss_p = out_p + (size_t)ROWS * 5;

    hipMemsetAsync(loss_p, 0, 4, stream);
    k_embed<<<ROWS * (DMODEL / 4) / 256, 256, 0, stream>>>(x, W_emb, b_emb, res);
    k_cvt_in<<<NLAYER * NPADW * DMODEL / 4 / 256, 256, 0, stream>>>(W_in, Wib);
    k_cvt_out<<<NLAYER * DMODEL * DINNER / 4 / 256, 256, 0, stream>>>(W_out, Wob);

    const int NBHC = BATCH * NHEADS * NCH;   // 1536
    for (int l = 0; l < NLAYER; ++l) {
        const float* cw_l = conv_w + (size_t)l * CONVDIM * 4;
        const float* cb_l = conv_b + (size_t)l * CONVDIM;
        k_rmsnorm<<<ROWS, 192, 0, stream>>>(res, bnw + l * DMODEL, hnb);
        dim3 g1(ROWS / 256, NPADW / 256);
        k_gemm<bf16, 256, 256, 512, false><<<g1, 512, 0, stream>>>(hnb, Wib + (size_t)l * NPADW * DMODEL, zx, DMODEL, NPAD, NPAD);
        k_convBC<<<ROWS * 32 / 256, 256, 0, stream>>>(zx, cw_l, cb_l, bc);
        k_prepL<<<NBHC, 256, 0, stream>>>(zx, bc, cw_l, cb_l, dt_bias + l * NHEADS, A_log + l * NHEADS,
                                          Sarr, dtc, Pcb, XT, Lbuf);
        k_scanB<<<BATCH * NHEADS * 4, 256, 0, stream>>>(Lbuf, Pcb);
        k_chunkY<<<NBHC, 512, 0, stream>>>(bc, Sarr, dtc, Dp + l * NHEADS, XT, Lbuf, ysb);
        k_gated<<<ROWS, 192, 0, stream>>>(ysb, zx, norm_w + l * DINNER, yfb);
        dim3 g2(ROWS / 128, DMODEL / 64);
        k_gemm<float, 128, 64, 256, true><<<g2, 256, 0, stream>>>(yfb, Wob + (size_t)l * DMODEL * DINNER, res, DINNER, DMODEL, DMODEL);
    }

    k_rmsnorm<<<ROWS, 192, 0, stream>>>(res, nfw, hnb);
    k_head<<<256, 256, 0, stream>>>(hnb, W_head, y, out_p, loss_p);
}